// Round 1
// baseline (650.687 us; speedup 1.0000x reference)
//
#include <hip/hip_runtime.h>
#include <math.h>

#define T_FRAMES 24000
#define NC1 97
#define NC2 300
#define NCC 397          // NC1 + NC2
#define NA 3806
#define H_DIM 909        // 512 + 97 + 300
#define COFF 512         // offset of clogit within feature row

// ---------------- block reduction helpers (256 threads = 4 waves) -----------

__device__ __forceinline__ float blockMax256(float v, float* sh) {
    const int tid = threadIdx.x;
    const int lane = tid & 63, wid = tid >> 6;
#pragma unroll
    for (int off = 32; off > 0; off >>= 1) v = fmaxf(v, __shfl_down(v, off));
    if (lane == 0) sh[wid] = v;
    __syncthreads();
    if (tid == 0) sh[0] = fmaxf(fmaxf(sh[0], sh[1]), fmaxf(sh[2], sh[3]));
    __syncthreads();
    float r = sh[0];
    __syncthreads();
    return r;
}

__device__ __forceinline__ float blockSum256(float v, float* sh) {
    const int tid = threadIdx.x;
    const int lane = tid & 63, wid = tid >> 6;
#pragma unroll
    for (int off = 32; off > 0; off >>= 1) v += __shfl_down(v, off);
    if (lane == 0) sh[wid] = v;
    __syncthreads();
    if (tid == 0) sh[0] = (sh[0] + sh[1]) + (sh[2] + sh[3]);
    __syncthreads();
    float r = sh[0];
    __syncthreads();
    return r;
}

// ---------------- kernel 0: pack (vid,nid) into one int ---------------------

__global__ __launch_bounds__(256) void k_pack(const int* __restrict__ vids,
                                              const int* __restrict__ nids,
                                              int* __restrict__ pk) {
    int a = blockIdx.x * 256 + threadIdx.x;
    if (a < NA) pk[a] = vids[a] | (nids[a] << 16);
}

// ---------------- kernel 1: per-frame stats + argmax ------------------------
// one block per frame; computes mV,lseV,mN,lseN and pred[t]

__global__ __launch_bounds__(256) void k_frame(const float* __restrict__ ff,
                                               const int* __restrict__ pk,
                                               float* __restrict__ fstats,
                                               int* __restrict__ pred) {
    const int t = blockIdx.x;
    const int tid = threadIdx.x;
    const float* row = ff + (size_t)t * H_DIM + COFF;

    __shared__ float lg[NCC];
    __shared__ float sred[4];
    __shared__ float sval[256];
    __shared__ int sidx[256];

    for (int i = tid; i < NCC; i += 256) lg[i] = row[i];
    __syncthreads();

    // verb logsumexp
    float v = -INFINITY;
    for (int i = tid; i < NC1; i += 256) v = fmaxf(v, lg[i]);
    float mV = blockMax256(v, sred);
    float s = 0.f;
    for (int i = tid; i < NC1; i += 256) s += expf(lg[i] - mV);
    float lseV = logf(blockSum256(s, sred));

    // noun logsumexp
    v = -INFINITY;
    for (int i = tid; i < NC2; i += 256) v = fmaxf(v, lg[NC1 + i]);
    float mN = blockMax256(v, sred);
    s = 0.f;
    for (int i = tid; i < NC2; i += 256) s += expf(lg[NC1 + i] - mN);
    float lseN = logf(blockSum256(s, sred));

    // convert raw logits -> log-probs in LDS
    for (int i = tid; i < NCC; i += 256) {
        float x = lg[i];
        lg[i] = (i < NC1) ? ((x - mV) - lseV) : ((x - mN) - lseN);
    }
    __syncthreads();

    // argmax over actions, first-occurrence tie-break (lowest index on ties)
    float bv = -INFINITY;
    int bi = NA;
    for (int a = tid; a < NA; a += 256) {
        int p = pk[a];
        float val = lg[p & 0xffff] + lg[NC1 + (p >> 16)];
        if (val > bv) { bv = val; bi = a; }   // strided ascending -> keeps first
    }
    sval[tid] = bv;
    sidx[tid] = bi;
    __syncthreads();
    for (int off = 128; off > 0; off >>= 1) {
        if (tid < off) {
            float v2 = sval[tid + off];
            int i2 = sidx[tid + off];
            if (v2 > sval[tid] || (v2 == sval[tid] && i2 < sidx[tid])) {
                sval[tid] = v2;
                sidx[tid] = i2;
            }
        }
        __syncthreads();
    }
    if (tid == 0) {
        pred[t] = sidx[0];
        fstats[t * 4 + 0] = mV;
        fstats[t * 4 + 1] = lseV;
        fstats[t * 4 + 2] = mN;
        fstats[t * 4 + 3] = lseN;
    }
}

// ---------------- kernel 2: single-block scan -> seg_id, seg_start, S -------

__global__ __launch_bounds__(1024) void k_scan(const int* __restrict__ pred,
                                               int* __restrict__ seg_id,
                                               int* __restrict__ seg_start,
                                               int* __restrict__ Scount) {
    const int tid = threadIdx.x;
    const int CH = (T_FRAMES + 1023) / 1024;  // 24
    const int base = tid * CH;

    int cnt = 0;
    for (int k = 0; k < CH; k++) {
        int t = base + k;
        if (t > 0 && t < T_FRAMES && pred[t] != pred[t - 1]) cnt++;
    }

    __shared__ int wsum[16];
    const int lane = tid & 63, wid = tid >> 6;
    int inc = cnt;
#pragma unroll
    for (int d = 1; d < 64; d <<= 1) {
        int n = __shfl_up(inc, d);
        if (lane >= d) inc += n;
    }
    if (lane == 63) wsum[wid] = inc;
    __syncthreads();
    if (tid == 0) {
        int acc = 0;
        for (int i = 0; i < 16; i++) { int x = wsum[i]; wsum[i] = acc; acc += x; }
    }
    __syncthreads();
    int sid = wsum[wid] + inc - cnt;  // exclusive prefix = segment id at chunk start

    for (int k = 0; k < CH; k++) {
        int t = base + k;
        if (t >= T_FRAMES) break;
        if (t == 0) {
            seg_start[0] = 0;
        } else if (pred[t] != pred[t - 1]) {
            sid++;
            seg_start[sid] = t;
        }
        seg_id[t] = sid;
        if (t == T_FRAMES - 1) *Scount = sid + 1;
    }
}

// ---------------- kernel 3: per-segment mean + log-softmax table ------------
// one block per (potential) segment; early-exit past S

__global__ __launch_bounds__(256) void k_seg(const float* __restrict__ ff,
                                             const int* __restrict__ seg_start,
                                             const int* __restrict__ Scount,
                                             float* __restrict__ seg_lg) {
    const int s = blockIdx.x;
    const int S = *Scount;
    if (s >= S) return;
    const int tid = threadIdx.x;
    const int start = seg_start[s];
    const int end = (s + 1 < S) ? seg_start[s + 1] : T_FRAMES;
    const int len = end - start;

    __shared__ float lg[NCC];
    __shared__ float sred[4];

    for (int c = tid; c < NCC; c += 256) {
        float sum = 0.f;
        const float* p = ff + (size_t)start * H_DIM + COFF + c;
        for (int k = 0; k < len; k++) sum += p[(size_t)k * H_DIM];
        lg[c] = sum / (float)len;
    }
    __syncthreads();

    float v = -INFINITY;
    for (int i = tid; i < NC1; i += 256) v = fmaxf(v, lg[i]);
    float mV = blockMax256(v, sred);
    float ssum = 0.f;
    for (int i = tid; i < NC1; i += 256) ssum += expf(lg[i] - mV);
    float lseV = logf(blockSum256(ssum, sred));

    v = -INFINITY;
    for (int i = tid; i < NC2; i += 256) v = fmaxf(v, lg[NC1 + i]);
    float mN = blockMax256(v, sred);
    ssum = 0.f;
    for (int i = tid; i < NC2; i += 256) ssum += expf(lg[NC1 + i] - mN);
    float lseN = logf(blockSum256(ssum, sred));

    float* dst = seg_lg + (size_t)s * NCC;
    for (int i = tid; i < NCC; i += 256) {
        float x = lg[i];
        dst[i] = (i < NC1) ? ((x - mV) - lseV) : ((x - mN) - lseN);
    }
}

// ---------------- kernel 4: fused output write ------------------------------
// one block per frame; out[t,a] = (fvlog[v]+fnlog[n]) + (svlog[v]+snlog[n])

__global__ __launch_bounds__(256) void k_out(const float* __restrict__ ff,
                                             const int* __restrict__ pk,
                                             const float* __restrict__ fstats,
                                             const int* __restrict__ seg_id,
                                             const float* __restrict__ seg_lg,
                                             float* __restrict__ out) {
    const int t = blockIdx.x;
    const int tid = threadIdx.x;
    const int s = seg_id[t];

    __shared__ float flg[NCC];
    __shared__ float slg[NCC];

    const float mV = fstats[t * 4 + 0];
    const float lseV = fstats[t * 4 + 1];
    const float mN = fstats[t * 4 + 2];
    const float lseN = fstats[t * 4 + 3];

    const float* row = ff + (size_t)t * H_DIM + COFF;
    const float* srow = seg_lg + (size_t)s * NCC;
    for (int i = tid; i < NCC; i += 256) {
        float x = row[i];
        flg[i] = (i < NC1) ? ((x - mV) - lseV) : ((x - mN) - lseN);
        slg[i] = srow[i];
    }
    __syncthreads();

    float* orow = out + (size_t)t * NA;
    for (int a = tid; a < NA; a += 256) {
        int p = pk[a];
        int vv = p & 0xffff, nn = p >> 16;
        orow[a] = (flg[vv] + flg[NC1 + nn]) + (slg[vv] + slg[NC1 + nn]);
    }
}

// ---------------- launcher --------------------------------------------------

extern "C" void kernel_launch(void* const* d_in, const int* in_sizes, int n_in,
                              void* d_out, int out_size, void* d_ws, size_t ws_size,
                              hipStream_t stream) {
    const float* ff = (const float*)d_in[0];
    const int* vids = (const int*)d_in[1];
    const int* nids = (const int*)d_in[2];
    float* out = (float*)d_out;

    char* ws = (char*)d_ws;
    size_t off = 0;
    float* fstats = (float*)(ws + off); off += (size_t)4 * T_FRAMES * 4;        // 384000
    int* pred = (int*)(ws + off);       off += (size_t)T_FRAMES * 4;            // 96000
    int* seg_id = (int*)(ws + off);     off += (size_t)T_FRAMES * 4;            // 96000
    int* seg_start = (int*)(ws + off);  off += (size_t)T_FRAMES * 4;            // 96000
    int* Scount = (int*)(ws + off);     off += 16;
    int* pk = (int*)(ws + off);         off += ((size_t)NA * 4 + 15) / 16 * 16; // packed actions
    float* seg_lg = (float*)(ws + off); off += (size_t)T_FRAMES * NCC * 4;      // ~38 MB

    k_pack<<<(NA + 255) / 256, 256, 0, stream>>>(vids, nids, pk);
    k_frame<<<T_FRAMES, 256, 0, stream>>>(ff, pk, fstats, pred);
    k_scan<<<1, 1024, 0, stream>>>(pred, seg_id, seg_start, Scount);
    k_seg<<<T_FRAMES, 256, 0, stream>>>(ff, seg_start, Scount, seg_lg);
    k_out<<<T_FRAMES, 256, 0, stream>>>(ff, pk, fstats, seg_id, seg_lg, out);
}